// Round 7
// baseline (475.715 us; speedup 1.0000x reference)
//
#include <hip/hip_runtime.h>
#include <hip/hip_bf16.h>
#include <stdint.h>

#define S_LEN   4096
#define DIN     1280
#define DOUT    1280
#define N_LORA  4
#define R_LORA  16
#define M_TOT   32768               // B*S = 8*4096
#define KC      (DIN + N_LORA*R_LORA)   // 1344
#define NR      64                  // N_LORA*R_LORA

typedef __attribute__((ext_vector_type(4))) float floatx4;
typedef __attribute__((ext_vector_type(8))) short shortx8;

typedef union { uint4 u; shortx8 s; } punx8;

static __device__ __forceinline__ unsigned short bf16_rne(float f) {
    union { float f; unsigned u; } v; v.f = f;
    unsigned u = v.u;
    u += 0x7fffu + ((u >> 16) & 1u);   // round-to-nearest-even
    return (unsigned short)(u >> 16);
}

static __device__ __forceinline__ void async16(const unsigned short* g, unsigned short* l) {
    __builtin_amdgcn_global_load_lds(
        (const __attribute__((address_space(1))) unsigned int*)g,
        (__attribute__((address_space(3))) unsigned int*)l, 16, 0, 0);
}

static __device__ __forceinline__ uint4 cvt8(const float* src) {
    const float4* p = (const float4*)src;
    float4 a = p[0], b = p[1];
    uint4 o;
    o.x = (unsigned)bf16_rne(a.x) | ((unsigned)bf16_rne(a.y) << 16);
    o.y = (unsigned)bf16_rne(a.z) | ((unsigned)bf16_rne(a.w) << 16);
    o.z = (unsigned)bf16_rne(b.x) | ((unsigned)bf16_rne(b.y) << 16);
    o.w = (unsigned)bf16_rne(b.z) | ((unsigned)bf16_rne(b.w) << 16);
    return o;
}

// counted vmcnt wait; raw barrier (no implicit vmcnt drain)
#define VMCNT(n) asm volatile("s_waitcnt vmcnt(" #n ")" ::: "memory")
static __device__ __forceinline__ void barx() {
    asm volatile("" ::: "memory");
    __builtin_amdgcn_s_barrier();
    asm volatile("" ::: "memory");
}

// ---- Kernel 2: Wcat[o, 0:1280] = W[o,:];  Wcat[o, 1280 + n*16 + r] = Bw[n,o,r]
__global__ __launch_bounds__(256) void k_build_wcat(const float* __restrict__ W,
                                                    const float* __restrict__ Bw,
                                                    unsigned short* __restrict__ Wcat) {
    int i = blockIdx.x * 256 + threadIdx.x;   // 215,040 threads
    int e = i * 8;
    int o = e / KC;
    int c = e - o * KC;                       // multiple of 8
    const float* src;
    if (c < DIN) {
        src = W + o * DIN + c;
    } else {
        int j = c - DIN;                      // 0..63, multiple of 8
        int n = j >> 4, r = j & 15;           // r in {0,8}
        src = Bw + (n * DOUT + o) * R_LORA + r;
    }
    *(uint4*)(Wcat + o * KC + c) = cvt8(src);
}

// ---- Kernel 3: A (4,16,1280) fp32 -> Abp fragment-major bf16
__global__ __launch_bounds__(256) void k_convert_abp(const float* __restrict__ A,
                                                     unsigned short* __restrict__ Abp) {
    int step = blockIdx.x;                    // 40 blocks
    int t = threadIdx.x;
    int ct = t >> 6, lane = t & 63;
    int mi = lane & 15, kq = lane >> 4;
    const float* src = A + (ct * 16 + mi) * DIN + step * 32 + kq * 8;
    *(uint4*)(Abp + ((size_t)(step * 4 + ct) * 64 + lane) * 8) = cvt8(src);
}

// ---- Kernel 4 (fused convert_x + lora_g): reads x fp32, converts to bf16
// in-register, uses converted frags for its MFMA, writes xb and g.
__global__ __launch_bounds__(1024) void k_lora_g(const float* __restrict__ x,
                                                 const unsigned short* __restrict__ Abp,
                                                 const float* __restrict__ scalings,
                                                 const float* __restrict__ masks,
                                                 unsigned short* __restrict__ g,
                                                 unsigned short* __restrict__ xb) {
    __shared__ float hs[4][64][64];           // [kg][row][rank] fp32 partials
    int tid = threadIdx.x;
    int wave = tid >> 6, lane = tid & 63;
    int kg = wave >> 2, wv = wave & 3;
    int mi = lane & 15, kq = lane >> 4;
    int m0 = blockIdx.x * 64;                 // 512 blocks

    const float* xrow = x + (size_t)(m0 + wv * 16 + mi) * DIN;
    unsigned short* xbrow = xb + (size_t)(m0 + wv * 16 + mi) * DIN;

    floatx4 acc[4] = {};
    for (int s = 0; s < 10; ++s) {
        int step = kg * 10 + s;               // global 32-wide k-step, 0..39
        int k = step * 32 + kq * 8;
        punx8 xp; xp.u = cvt8(xrow + k);      // fp32 -> bf16x8 in-register
        *(uint4*)(xbrow + k) = xp.u;          // side output: xb
        shortx8 xf = xp.s;
#pragma unroll
        for (int ct = 0; ct < 4; ++ct) {
            shortx8 bfr = *(const shortx8*)(Abp + ((size_t)(step * 4 + ct) * 64 + lane) * 8);
            acc[ct] = __builtin_amdgcn_mfma_f32_16x16x32_bf16(xf, bfr, acc[ct], 0, 0, 0);
        }
    }
#pragma unroll
    for (int ct = 0; ct < 4; ++ct)
#pragma unroll
        for (int reg = 0; reg < 4; ++reg)
            hs[kg][wv * 16 + kq * 4 + reg][ct * 16 + mi] = acc[ct][reg];
    __syncthreads();

    int r = tid >> 4;                         // 0..63 local row
    int c0 = (tid & 15) * 4;                  // 0..60 rank col (4-aligned)
    float4 s0 = *(const float4*)&hs[0][r][c0];
    float4 s1 = *(const float4*)&hs[1][r][c0];
    float4 s2 = *(const float4*)&hs[2][r][c0];
    float4 s3 = *(const float4*)&hs[3][r][c0];
    int n = c0 >> 4;                          // adapter (c0..c0+3 share it)
    int m = m0 + r;
    float wgt = scalings[n] * masks[n * S_LEN + (m & (S_LEN - 1))];
    float v0 = (s0.x + s1.x + s2.x + s3.x) * wgt;
    float v1 = (s0.y + s1.y + s2.y + s3.y) * wgt;
    float v2 = (s0.z + s1.z + s2.z + s3.z) * wgt;
    float v3 = (s0.w + s1.w + s2.w + s3.w) * wgt;
    uint2 packed;
    packed.x = (unsigned)bf16_rne(v0) | ((unsigned)bf16_rne(v1) << 16);
    packed.y = (unsigned)bf16_rne(v2) | ((unsigned)bf16_rne(v3) << 16);
    *(uint2*)(g + (size_t)m * NR + c0) = packed;
}

// ---- Kernel 5: out = [xb | g] @ Wcat^T + bias  (M=32768, N=1280, K=1344)
// R7 CHANGE: ONE barrier per K-tile, full-tile burst (no phase lockstep).
// R3-R6 data: per-phase barriers pin all 8 waves in lockstep; each 1363-cyc
// phase = 621 MFMA + ~500 LDS-read + ~180 barrier, fully SERIAL, and every
// rearrangement that kept phase granularity (R4/R5/R6) was a no-op. Here the
// whole tile (24 ds_reads + 64 MFMAs per wave) is one unfragmented region:
// the compiler's fine-grained lgkmcnt(N) interleave (m97 asm evidence) lets
// early MFMAs run while later reads are serviced; LDS pipe (~2500 cyc/tile)
// and matrix pipe (~2484 cyc/tile) overlap instead of summing.
// Tile body: { stage(t+1) -> buf^1 (8 async16, issued FIRST, ~2500 cyc of
// cover, L2-hot); reads+MFMAs from buf (compiler-scheduled); VMCNT(0) (free:
// loads long landed); barx }. Single-barrier safety: a wave's tile-t reads
// retire before its MFMAs, which precede its barrier arrival; the overwrite
// of buf[t&1] is issued only after the NEXT barrier-crossing -> no race.
// Registers: aR[2][8] + b[2][4] + acc[8][4] ~ 244 VGPR (2 waves/SIMD budget
// 256) — watch VGPR_Count for spill. Swizzle/geometry/epilogue = R6.
__global__ __launch_bounds__(512, 2) void k_main_gemm(const unsigned short* __restrict__ xb,
                                                      const unsigned short* __restrict__ g,
                                                      const unsigned short* __restrict__ Wcat,
                                                      const float* __restrict__ bias,
                                                      float* __restrict__ out) {
    __shared__ alignas(16) unsigned short As[2][256 * 64];
    __shared__ alignas(16) unsigned short Bs[2][256 * 64];

    const int tid = threadIdx.x;
    const int wave = tid >> 6, lane = tid & 63;
    const int wm = wave >> 2, wn = wave & 3;        // 2M x 4N wave grid
    const int mi = lane & 15, kq = lane >> 4;

    // XCD-bijective swizzle: 640 blocks = 8 XCDs x 80 slots = 16 row-tiles x 5 col-tiles,
    // col fastest -> same-row blocks co-resident, xb row-panel L2-hot.
    int bx = blockIdx.x;
    int xcd = bx & 7, slot = bx >> 3;               // slot 0..79
    int srb = slot / 5;
    const int m0 = (xcd * 16 + srb) * 256;
    const int n0 = (slot - srb * 5) * 256;

    // staging: chunk = 64 rows x 64 cols = 8 KB = 1 gload_lds per thread.
    const int tr = tid >> 3;                        // row within chunk
    const int ts = (tid & 7) ^ (tr & 7);            // pre-swizzled 16B column slot

    const unsigned short* pA = xb   + (size_t)(m0 + tr) * DIN + ts * 8;
    const unsigned short* pG = g    + (size_t)(m0 + tr) * NR  + ts * 8;
    const unsigned short* pB = Wcat + (size_t)(n0 + tr) * KC  + ts * 8;

    // read-side swizzled lane offsets (row&7 == mi&7 for all fragment rows)
    const int swz  = mi & 7;
    const int loK0 = mi * 128 + (((0) + kq) ^ swz) * 16;   // k-sub 0
    const int loK1 = mi * 128 + (((4) + kq) ^ swz) * 16;   // k-sub 1
    const int rbA  = (wm * 128) * 128;              // wave A row-block byte offset
    const int rbB  = (wn * 64) * 128;               // wave B row-block byte offset

    floatx4 acc[8][4] = {};
    shortx8 aR[2][8];                               // A frags for both halves
    shortx8 b[2][4];                                // B frags for both halves

    auto stA = [&](int t, int h) {                  // stage A half h of tile t -> buf t&1
        unsigned short* d = &As[t & 1][(h * 128) * 64 + tid * 8];
        if (t < 20) {
            const unsigned short* s = pA + (size_t)(h * 128) * DIN + t * 64;
            async16(s, d);
            async16(s + (size_t)64 * DIN, d + 64 * 64);
        } else {                                    // tile 20 = LoRA columns from g
            const unsigned short* s = pG + (size_t)(h * 128) * NR;
            async16(s, d);
            async16(s + (size_t)64 * NR, d + 64 * 64);
        }
    };
    auto stB = [&](int t, int h) {
        const unsigned short* s = pB + (size_t)(h * 128) * KC + t * 64;
        unsigned short* d = &Bs[t & 1][(h * 128) * 64 + tid * 8];
        async16(s, d);
        async16(s + (size_t)64 * KC, d + 64 * 64);
    };

#define READ_A(bufb, mh)  _Pragma("unroll") \
    for (int fm = 0; fm < 4; ++fm) { \
        const char* p = (const char*)As[bufb] + rbA + ((mh) * 64 + fm * 16) * 128; \
        aR[(mh)][fm * 2 + 0] = *(const shortx8*)(p + loK0); \
        aR[(mh)][fm * 2 + 1] = *(const shortx8*)(p + loK1); \
    }
#define READ_B(bufb, nh)  _Pragma("unroll") \
    for (int fn = 0; fn < 2; ++fn) { \
        const char* p = (const char*)Bs[bufb] + rbB + ((nh) * 32 + fn * 16) * 128; \
        b[nh][fn * 2 + 0] = *(const shortx8*)(p + loK0); \
        b[nh][fn * 2 + 1] = *(const shortx8*)(p + loK1); \
    }
#define MFMA16(mh, nh)  do { \
    _Pragma("unroll") \
    for (int fm = 0; fm < 4; ++fm) \
        _Pragma("unroll") \
        for (int fn = 0; fn < 2; ++fn) { \
            acc[(mh)*4+fm][(nh)*2+fn] = __builtin_amdgcn_mfma_f32_16x16x32_bf16( \
                aR[(mh)][fm*2+0], b[nh][fn*2+0], acc[(mh)*4+fm][(nh)*2+fn], 0, 0, 0); \
            acc[(mh)*4+fm][(nh)*2+fn] = __builtin_amdgcn_mfma_f32_16x16x32_bf16( \
                aR[(mh)][fm*2+1], b[nh][fn*2+1], acc[(mh)*4+fm][(nh)*2+fn], 0, 0, 0); \
        } \
    } while (0)

    // prologue: tile 0 -> buf0, drain, barrier.
    stA(0, 0); stA(0, 1); stB(0, 0); stB(0, 1);
    VMCNT(0);
    barx();

    for (int t = 0; t < 21; ++t) {
        const int cur = t & 1;
        // stage next tile into the other buffer FIRST (max latency cover)
        if (t < 20) {
            stA(t + 1, 0); stA(t + 1, 1);
            stB(t + 1, 0); stB(t + 1, 1);
        }
        // full-tile reads + MFMAs, one unfragmented region (compiler interleaves)
        READ_A(cur, 0);
        READ_B(cur, 0);
        READ_B(cur, 1);
        __builtin_amdgcn_s_setprio(1);
        MFMA16(0, 0);
        MFMA16(0, 1);
        __builtin_amdgcn_s_setprio(0);
        READ_A(cur, 1);
        __builtin_amdgcn_s_setprio(1);
        MFMA16(1, 0);
        MFMA16(1, 1);
        __builtin_amdgcn_s_setprio(0);
        // stage loads were issued ~2500 cyc ago -> this drain is ~free
        VMCNT(0);
        barx();
    }

    // ---- epilogue: C/D layout col = lane&15, row = (lane>>4)*4 + reg
    float bv[4];
#pragma unroll
    for (int nf = 0; nf < 4; ++nf)
        bv[nf] = bias[n0 + wn * 64 + (nf >> 1) * 32 + (nf & 1) * 16 + mi];
#pragma unroll
    for (int mf = 0; mf < 8; ++mf) {
        const int row = m0 + wm * 128 + (mf >> 2) * 64 + (mf & 3) * 16 + kq * 4;
#pragma unroll
        for (int nf = 0; nf < 4; ++nf) {
            const int col = n0 + wn * 64 + (nf >> 1) * 32 + (nf & 1) * 16 + mi;
            float* op = out + (size_t)row * DOUT + col;
#pragma unroll
            for (int reg = 0; reg < 4; ++reg)
                op[(size_t)reg * DOUT] = acc[mf][nf][reg] + bv[nf];
        }
    }
#undef READ_A
#undef READ_B
#undef MFMA16
}

extern "C" void kernel_launch(void* const* d_in, const int* in_sizes, int n_in,
                              void* d_out, int out_size, void* d_ws, size_t ws_size,
                              hipStream_t stream) {
    const float* x     = (const float*)d_in[0];  // (8,4096,1280)
    const float* W     = (const float*)d_in[1];  // (1280,1280)
    const float* bias  = (const float*)d_in[2];  // (1280,)
    const float* A     = (const float*)d_in[3];  // (4,16,1280)
    const float* Bw    = (const float*)d_in[4];  // (4,1280,16)
    const float* scal  = (const float*)d_in[5];  // (4,)
    const float* masks = (const float*)d_in[6];  // (4,4096)
    float* out = (float*)d_out;

    unsigned short* xb   = (unsigned short*)d_ws;            // 32768 x 1280 bf16
    unsigned short* g    = xb + (size_t)M_TOT * DIN;         // 32768 x 64 bf16
    unsigned short* Wcat = g + (size_t)M_TOT * NR;           // 1280 x 1344 bf16
    unsigned short* Abp  = Wcat + (size_t)DOUT * KC;         // 40*4*64*8 bf16

    k_build_wcat<<<(DOUT * KC) / (8 * 256), 256, 0, stream>>>(W, Bw, Wcat);
    k_convert_abp<<<DIN / 32, 256, 0, stream>>>(A, Abp);
    k_lora_g<<<M_TOT / 64, 1024, 0, stream>>>(x, Abp, scal, masks, g, xb);
    k_main_gemm<<<(M_TOT / 256) * (DOUT / 256), 512, 0, stream>>>(xb, g, Wcat, bias, out);
}

// Round 8
// 448.089 us; speedup vs baseline: 1.0617x; 1.0617x over previous
//
#include <hip/hip_runtime.h>
#include <hip/hip_bf16.h>
#include <stdint.h>

#define S_LEN   4096
#define DIN     1280
#define DOUT    1280
#define N_LORA  4
#define R_LORA  16
#define M_TOT   32768               // B*S = 8*4096
#define KC      (DIN + N_LORA*R_LORA)   // 1344
#define NR      64                  // N_LORA*R_LORA

typedef __attribute__((ext_vector_type(4))) float floatx4;
typedef __attribute__((ext_vector_type(8))) short shortx8;

typedef union { uint4 u; shortx8 s; } punx8;

static __device__ __forceinline__ unsigned short bf16_rne(float f) {
    union { float f; unsigned u; } v; v.f = f;
    unsigned u = v.u;
    u += 0x7fffu + ((u >> 16) & 1u);   // round-to-nearest-even
    return (unsigned short)(u >> 16);
}

static __device__ __forceinline__ void async16(const unsigned short* g, unsigned short* l) {
    __builtin_amdgcn_global_load_lds(
        (const __attribute__((address_space(1))) unsigned int*)g,
        (__attribute__((address_space(3))) unsigned int*)l, 16, 0, 0);
}

static __device__ __forceinline__ uint4 cvt8(const float* src) {
    const float4* p = (const float4*)src;
    float4 a = p[0], b = p[1];
    uint4 o;
    o.x = (unsigned)bf16_rne(a.x) | ((unsigned)bf16_rne(a.y) << 16);
    o.y = (unsigned)bf16_rne(a.z) | ((unsigned)bf16_rne(a.w) << 16);
    o.z = (unsigned)bf16_rne(b.x) | ((unsigned)bf16_rne(b.y) << 16);
    o.w = (unsigned)bf16_rne(b.z) | ((unsigned)bf16_rne(b.w) << 16);
    return o;
}

// counted vmcnt wait; raw barrier (no implicit vmcnt drain)
#define VMCNT(n) asm volatile("s_waitcnt vmcnt(" #n ")" ::: "memory")
static __device__ __forceinline__ void barx() {
    asm volatile("" ::: "memory");
    __builtin_amdgcn_s_barrier();
    asm volatile("" ::: "memory");
}

// ---- Kernel 2: Wcat[o, 0:1280] = W[o,:];  Wcat[o, 1280 + n*16 + r] = Bw[n,o,r]
__global__ __launch_bounds__(256) void k_build_wcat(const float* __restrict__ W,
                                                    const float* __restrict__ Bw,
                                                    unsigned short* __restrict__ Wcat) {
    int i = blockIdx.x * 256 + threadIdx.x;   // 215,040 threads
    int e = i * 8;
    int o = e / KC;
    int c = e - o * KC;                       // multiple of 8
    const float* src;
    if (c < DIN) {
        src = W + o * DIN + c;
    } else {
        int j = c - DIN;                      // 0..63, multiple of 8
        int n = j >> 4, r = j & 15;           // r in {0,8}
        src = Bw + (n * DOUT + o) * R_LORA + r;
    }
    *(uint4*)(Wcat + o * KC + c) = cvt8(src);
}

// ---- Kernel 3: A (4,16,1280) fp32 -> Abp fragment-major bf16
__global__ __launch_bounds__(256) void k_convert_abp(const float* __restrict__ A,
                                                     unsigned short* __restrict__ Abp) {
    int step = blockIdx.x;                    // 40 blocks
    int t = threadIdx.x;
    int ct = t >> 6, lane = t & 63;
    int mi = lane & 15, kq = lane >> 4;
    const float* src = A + (ct * 16 + mi) * DIN + step * 32 + kq * 8;
    *(uint4*)(Abp + ((size_t)(step * 4 + ct) * 64 + lane) * 8) = cvt8(src);
}

// ---- Kernel 4 (R8: fused convert_x + lora_g, WRITE-COALESCED):
// R5/R6's fusion wrote xb from the MFMA fragment path — 16-B stores at a
// 16-row scatter (stride 2560 B), uncoalesced; measured as a net LOSS vs the
// separate streaming kernel (R4 non-gemm 294 vs R6 306). Fix: split x's two
// roles. Phase (a): each block linearly converts its own 64x1280 slab
// (10 x 16-B stores/thread, perfectly coalesced — the old k_convert_x, done
// block-locally). Phase (b): the MFMA path re-reads x in fragment order; the
// second read hits L2/L3 (x = 168 MB fits the 256-MB L3). No scattered
// stores remain; one kernel, one launch.
__global__ __launch_bounds__(1024) void k_lora_g(const float* __restrict__ x,
                                                 const unsigned short* __restrict__ Abp,
                                                 const float* __restrict__ scalings,
                                                 const float* __restrict__ masks,
                                                 unsigned short* __restrict__ g,
                                                 unsigned short* __restrict__ xb) {
    __shared__ float hs[4][64][64];           // [kg][row][rank] fp32 partials
    int tid = threadIdx.x;
    int wave = tid >> 6, lane = tid & 63;
    int kg = wave >> 2, wv = wave & 3;
    int mi = lane & 15, kq = lane >> 4;
    int m0 = blockIdx.x * 64;                 // 512 blocks

    // ---- phase (a): coalesced convert-store of this block's slab
    {
        size_t base = (size_t)m0 * DIN;       // 64*1280 = 81920 elems = 10*1024*8
#pragma unroll
        for (int it = 0; it < 10; ++it) {
            size_t e = base + ((size_t)it * 1024 + tid) * 8;
            *(uint4*)(xb + e) = cvt8(x + e);
        }
    }

    // ---- phase (b): LoRA h = x @ A^T via MFMA (x re-read fragment-order, L2/L3-hot)
    const float* xrow = x + (size_t)(m0 + wv * 16 + mi) * DIN;

    floatx4 acc[4] = {};
    for (int s = 0; s < 10; ++s) {
        int step = kg * 10 + s;               // global 32-wide k-step, 0..39
        int k = step * 32 + kq * 8;
        punx8 xp; xp.u = cvt8(xrow + k);      // fp32 -> bf16x8 in-register
        shortx8 xf = xp.s;
#pragma unroll
        for (int ct = 0; ct < 4; ++ct) {
            shortx8 bfr = *(const shortx8*)(Abp + ((size_t)(step * 4 + ct) * 64 + lane) * 8);
            acc[ct] = __builtin_amdgcn_mfma_f32_16x16x32_bf16(xf, bfr, acc[ct], 0, 0, 0);
        }
    }
#pragma unroll
    for (int ct = 0; ct < 4; ++ct)
#pragma unroll
        for (int reg = 0; reg < 4; ++reg)
            hs[kg][wv * 16 + kq * 4 + reg][ct * 16 + mi] = acc[ct][reg];
    __syncthreads();

    int r = tid >> 4;                         // 0..63 local row
    int c0 = (tid & 15) * 4;                  // 0..60 rank col (4-aligned)
    float4 s0 = *(const float4*)&hs[0][r][c0];
    float4 s1 = *(const float4*)&hs[1][r][c0];
    float4 s2 = *(const float4*)&hs[2][r][c0];
    float4 s3 = *(const float4*)&hs[3][r][c0];
    int n = c0 >> 4;                          // adapter (c0..c0+3 share it)
    int m = m0 + r;
    float wgt = scalings[n] * masks[n * S_LEN + (m & (S_LEN - 1))];
    float v0 = (s0.x + s1.x + s2.x + s3.x) * wgt;
    float v1 = (s0.y + s1.y + s2.y + s3.y) * wgt;
    float v2 = (s0.z + s1.z + s2.z + s3.z) * wgt;
    float v3 = (s0.w + s1.w + s2.w + s3.w) * wgt;
    uint2 packed;
    packed.x = (unsigned)bf16_rne(v0) | ((unsigned)bf16_rne(v1) << 16);
    packed.y = (unsigned)bf16_rne(v2) | ((unsigned)bf16_rne(v3) << 16);
    *(uint2*)(g + (size_t)m * NR + c0) = packed;
}

// ---- Kernel 5: out = [xb | g] @ Wcat^T + bias  (M=32768, N=1280, K=1344)
// R6 structure UNCHANGED (best measured: 143 µs across R3/R4/R6; R5/R7
// coarsenings and R4 read-pipelining all neutral-or-worse — this 8-phase
// template is at its local optimum for this shape; see round journal).
// 8 waves (2M x 4N), BM=BN=256, BK=64, 2 K-tiles/iter, 8 phases/iter.
// Stage slots:  ph0: A(T1)h1   ph2: B(N0)h0   ph3: B(N0)h1+A(N0)h0 [VMCNT(6)]
//               ph4: A(N0)h1   ph6: B(N1)h0   ph7: B(N1)h1+A(N1)h0 [VMCNT(6)]
// VMCNT before bar2 (race-free placement). Compiler inserts fine-grained
// lgkm waits (R6-verified equal to explicit lgkmcnt(0)). LDS swizzle:
// 16B-slot ^ (row&7), pre-swizzled global source; 0 conflicts measured.
__global__ __launch_bounds__(512, 2) void k_main_gemm(const unsigned short* __restrict__ xb,
                                                      const unsigned short* __restrict__ g,
                                                      const unsigned short* __restrict__ Wcat,
                                                      const float* __restrict__ bias,
                                                      float* __restrict__ out) {
    __shared__ alignas(16) unsigned short As[2][256 * 64];
    __shared__ alignas(16) unsigned short Bs[2][256 * 64];

    const int tid = threadIdx.x;
    const int wave = tid >> 6, lane = tid & 63;
    const int wm = wave >> 2, wn = wave & 3;        // 2M x 4N wave grid
    const int mi = lane & 15, kq = lane >> 4;

    // XCD-bijective swizzle: 640 blocks = 8 XCDs x 80 slots = 16 row-tiles x 5 col-tiles,
    // col fastest -> same-row blocks co-resident, xb row-panel L2-hot.
    int bx = blockIdx.x;
    int xcd = bx & 7, slot = bx >> 3;               // slot 0..79
    int srb = slot / 5;
    const int m0 = (xcd * 16 + srb) * 256;
    const int n0 = (slot - srb * 5) * 256;

    // staging: chunk = 64 rows x 64 cols = 8 KB = 1 gload_lds per thread.
    const int tr = tid >> 3;                        // row within chunk
    const int ts = (tid & 7) ^ (tr & 7);            // pre-swizzled 16B column slot

    const unsigned short* pA = xb   + (size_t)(m0 + tr) * DIN + ts * 8;
    const unsigned short* pG = g    + (size_t)(m0 + tr) * NR  + ts * 8;
    const unsigned short* pB = Wcat + (size_t)(n0 + tr) * KC  + ts * 8;

    // read-side swizzled lane offsets (row&7 == mi&7 for all fragment rows)
    const int swz  = mi & 7;
    const int loK0 = mi * 128 + (((0) + kq) ^ swz) * 16;   // k-sub 0
    const int loK1 = mi * 128 + (((4) + kq) ^ swz) * 16;   // k-sub 1
    const int rbA  = (wm * 128) * 128;              // wave A row-block byte offset
    const int rbB  = (wn * 64) * 128;               // wave B row-block byte offset

    floatx4 acc[8][4] = {};
    shortx8 a[8];                                   // current A-half: 4 m-frags x 2 ksubs
    shortx8 b[2][4];                                // B frags, ping-pong by nh

    auto stA = [&](int t, int h) {                  // stage A half h of tile t -> buf t&1
        unsigned short* d = &As[t & 1][(h * 128) * 64 + tid * 8];
        if (t < 20) {
            const unsigned short* s = pA + (size_t)(h * 128) * DIN + t * 64;
            async16(s, d);
            async16(s + (size_t)64 * DIN, d + 64 * 64);
        } else {                                    // tile 20 = LoRA columns from g
            const unsigned short* s = pG + (size_t)(h * 128) * NR;
            async16(s, d);
            async16(s + (size_t)64 * NR, d + 64 * 64);
        }
    };
    auto stB = [&](int t, int h) {
        const unsigned short* s = pB + (size_t)(h * 128) * KC + t * 64;
        unsigned short* d = &Bs[t & 1][(h * 128) * 64 + tid * 8];
        async16(s, d);
        async16(s + (size_t)64 * KC, d + 64 * 64);
    };

#define READ_A(bufb, mh)  _Pragma("unroll") \
    for (int fm = 0; fm < 4; ++fm) { \
        const char* p = (const char*)As[bufb] + rbA + ((mh) * 64 + fm * 16) * 128; \
        a[fm * 2 + 0] = *(const shortx8*)(p + loK0); \
        a[fm * 2 + 1] = *(const shortx8*)(p + loK1); \
    }
#define READ_B(bufb, nh)  _Pragma("unroll") \
    for (int fn = 0; fn < 2; ++fn) { \
        const char* p = (const char*)Bs[bufb] + rbB + ((nh) * 32 + fn * 16) * 128; \
        b[nh][fn * 2 + 0] = *(const shortx8*)(p + loK0); \
        b[nh][fn * 2 + 1] = *(const shortx8*)(p + loK1); \
    }
#define MFMA16(mh, nh)  do { __builtin_amdgcn_s_setprio(1); \
    _Pragma("unroll") \
    for (int fm = 0; fm < 4; ++fm) \
        _Pragma("unroll") \
        for (int fn = 0; fn < 2; ++fn) { \
            acc[(mh)*4+fm][(nh)*2+fn] = __builtin_amdgcn_mfma_f32_16x16x32_bf16( \
                a[fm*2+0], b[nh][fn*2+0], acc[(mh)*4+fm][(nh)*2+fn], 0, 0, 0); \
            acc[(mh)*4+fm][(nh)*2+fn] = __builtin_amdgcn_mfma_f32_16x16x32_bf16( \
                a[fm*2+1], b[nh][fn*2+1], acc[(mh)*4+fm][(nh)*2+fn], 0, 0, 0); \
        } \
    __builtin_amdgcn_s_setprio(0); } while (0)

    // prologue: tile0 (8 loads) then tile1's {Bh0, Bh1, Ah0} (6 loads).
    // VMCNT(6) -> tile0 landed.
    stA(0, 0); stA(0, 1); stB(0, 0); stB(0, 1);
    stB(1, 0); stB(1, 1); stA(1, 0);
    VMCNT(6);
    barx();

    for (int it = 0; it < 10; ++it) {
        const int T1 = 2 * it + 1, N0 = 2 * it + 2, N1 = 2 * it + 3;
        const bool lastI = (it == 9);

        // ---- phase 0: tile T0 (buf0) quad(0,0); stage A(T1)h1
        READ_A(0, 0); READ_B(0, 0);
        stA(T1, 1);
        barx();
        MFMA16(0, 0);
        barx();
        // ---- phase 1: quad(0,1); NO stage
        READ_B(0, 1);
        barx();
        MFMA16(0, 1);
        barx();
        // ---- phase 2: quad(1,0); B(buf0) freed after ph1 -> stage B(N0)h0
        READ_A(0, 1);
        stB(N0, 0);
        barx();
        MFMA16(1, 0);
        barx();
        // ---- phase 3: quad(1,1); A(buf0) freed after ph2 -> B(N0)h1 + A(N0)h0;
        //      VMCNT(6) before bar2: tile T1 (oldest 8) fully landed
        stB(N0, 1); stA(N0, 0);
        barx();
        MFMA16(1, 1);
        VMCNT(6);
        barx();
        // ---- phase 4: tile T1 (buf1) quad(0,0); stage A(N0)h1
        READ_A(1, 0); READ_B(1, 0);
        stA(N0, 1);
        barx();
        MFMA16(0, 0);
        barx();
        // ---- phase 5: quad(0,1); NO stage
        READ_B(1, 1);
        barx();
        MFMA16(0, 1);
        barx();
        // ---- phase 6: quad(1,0); B(buf1) freed after ph5 -> stage B(N1)h0
        READ_A(1, 1);
        if (!lastI) stB(N1, 0);
        barx();
        MFMA16(1, 0);
        barx();
        // ---- phase 7: quad(1,1); A(buf1) freed after ph6 -> B(N1)h1 + A(N1)h0;
        //      VMCNT(6) before bar2: tile N0 fully landed
        if (!lastI) { stB(N1, 1); stA(N1, 0); }
        barx();
        MFMA16(1, 1);
        if (lastI) { VMCNT(0); } else { VMCNT(6); }
        barx();
    }

    // ---- tail: tile 20 (buf0), stage-free; compiler inserts the lgkm waits.
    READ_A(0, 0); READ_B(0, 0);
    MFMA16(0, 0);
    READ_B(0, 1);
    MFMA16(0, 1);
    READ_A(0, 1);
    MFMA16(1, 0);
    MFMA16(1, 1);

    // ---- epilogue: C/D layout col = lane&15, row = (lane>>4)*4 + reg
    float bv[4];
#pragma unroll
    for (int nf = 0; nf < 4; ++nf)
        bv[nf] = bias[n0 + wn * 64 + (nf >> 1) * 32 + (nf & 1) * 16 + mi];
#pragma unroll
    for (int mf = 0; mf < 8; ++mf) {
        const int row = m0 + wm * 128 + (mf >> 2) * 64 + (mf & 3) * 16 + kq * 4;
#pragma unroll
        for (int nf = 0; nf < 4; ++nf) {
            const int col = n0 + wn * 64 + (nf >> 1) * 32 + (nf & 1) * 16 + mi;
            float* op = out + (size_t)row * DOUT + col;
#pragma unroll
            for (int reg = 0; reg < 4; ++reg)
                op[(size_t)reg * DOUT] = acc[mf][nf][reg] + bv[nf];
        }
    }
#undef READ_A
#undef READ_B
#undef MFMA16
}

extern "C" void kernel_launch(void* const* d_in, const int* in_sizes, int n_in,
                              void* d_out, int out_size, void* d_ws, size_t ws_size,
                              hipStream_t stream) {
    const float* x     = (const float*)d_in[0];  // (8,4096,1280)
    const float* W     = (const float*)d_in[1];  // (1280,1280)
    const float* bias  = (const float*)d_in[2];  // (1280,)
    const float* A     = (const float*)d_in[3];  // (4,16,1280)
    const float* Bw    = (const float*)d_in[4];  // (4,1280,16)
    const float* scal  = (const float*)d_in[5];  // (4,)
    const float* masks = (const float*)d_in[6];  // (4,4096)
    float* out = (float*)d_out;

    unsigned short* xb   = (unsigned short*)d_ws;            // 32768 x 1280 bf16
    unsigned short* g    = xb + (size_t)M_TOT * DIN;         // 32768 x 64 bf16
    unsigned short* Wcat = g + (size_t)M_TOT * NR;           // 1280 x 1344 bf16
    unsigned short* Abp  = Wcat + (size_t)DOUT * KC;         // 40*4*64*8 bf16

    k_build_wcat<<<(DOUT * KC) / (8 * 256), 256, 0, stream>>>(W, Bw, Wcat);
    k_convert_abp<<<DIN / 32, 256, 0, stream>>>(A, Abp);
    k_lora_g<<<M_TOT / 64, 1024, 0, stream>>>(x, Abp, scal, masks, g, xb);
    k_main_gemm<<<(M_TOT / 256) * (DOUT / 256), 512, 0, stream>>>(xb, g, Wcat, bias, out);
}

// Round 9
// 438.360 us; speedup vs baseline: 1.0852x; 1.0222x over previous
//
#include <hip/hip_runtime.h>
#include <hip/hip_bf16.h>
#include <stdint.h>

#define S_LEN   4096
#define DIN     1280
#define DOUT    1280
#define N_LORA  4
#define R_LORA  16
#define M_TOT   32768               // B*S = 8*4096
#define KC      (DIN + N_LORA*R_LORA)   // 1344
#define NR      64                  // N_LORA*R_LORA

typedef __attribute__((ext_vector_type(4))) float floatx4;
typedef __attribute__((ext_vector_type(8))) short shortx8;

typedef union { uint4 u; shortx8 s; } punx8;

static __device__ __forceinline__ unsigned short bf16_rne(float f) {
    union { float f; unsigned u; } v; v.f = f;
    unsigned u = v.u;
    u += 0x7fffu + ((u >> 16) & 1u);   // round-to-nearest-even
    return (unsigned short)(u >> 16);
}

static __device__ __forceinline__ void async16(const unsigned short* g, unsigned short* l) {
    __builtin_amdgcn_global_load_lds(
        (const __attribute__((address_space(1))) unsigned int*)g,
        (__attribute__((address_space(3))) unsigned int*)l, 16, 0, 0);
}

static __device__ __forceinline__ uint4 cvt8(const float* src) {
    const float4* p = (const float4*)src;
    float4 a = p[0], b = p[1];
    uint4 o;
    o.x = (unsigned)bf16_rne(a.x) | ((unsigned)bf16_rne(a.y) << 16);
    o.y = (unsigned)bf16_rne(a.z) | ((unsigned)bf16_rne(a.w) << 16);
    o.z = (unsigned)bf16_rne(b.x) | ((unsigned)bf16_rne(b.y) << 16);
    o.w = (unsigned)bf16_rne(b.z) | ((unsigned)bf16_rne(b.w) << 16);
    return o;
}

static __device__ __forceinline__ uint2 cvt4(float4 v) {
    uint2 o;
    o.x = (unsigned)bf16_rne(v.x) | ((unsigned)bf16_rne(v.y) << 16);
    o.y = (unsigned)bf16_rne(v.z) | ((unsigned)bf16_rne(v.w) << 16);
    return o;
}

// counted vmcnt wait; raw barrier (no implicit vmcnt drain)
#define VMCNT(n) asm volatile("s_waitcnt vmcnt(" #n ")" ::: "memory")
static __device__ __forceinline__ void barx() {
    asm volatile("" ::: "memory");
    __builtin_amdgcn_s_barrier();
    asm volatile("" ::: "memory");
}

// ---- Kernel 2: Wcat[o, 0:1280] = W[o,:];  Wcat[o, 1280 + n*16 + r] = Bw[n,o,r]
__global__ __launch_bounds__(256) void k_build_wcat(const float* __restrict__ W,
                                                    const float* __restrict__ Bw,
                                                    unsigned short* __restrict__ Wcat) {
    int i = blockIdx.x * 256 + threadIdx.x;   // 215,040 threads
    int e = i * 8;
    int o = e / KC;
    int c = e - o * KC;                       // multiple of 8
    const float* src;
    if (c < DIN) {
        src = W + o * DIN + c;
    } else {
        int j = c - DIN;                      // 0..63, multiple of 8
        int n = j >> 4, r = j & 15;           // r in {0,8}
        src = Bw + (n * DOUT + o) * R_LORA + r;
    }
    *(uint4*)(Wcat + o * KC + c) = cvt8(src);
}

// ---- Kernel 3: A (4,16,1280) fp32 -> Abp fragment-major bf16
__global__ __launch_bounds__(256) void k_convert_abp(const float* __restrict__ A,
                                                     unsigned short* __restrict__ Abp) {
    int step = blockIdx.x;                    // 40 blocks
    int t = threadIdx.x;
    int ct = t >> 6, lane = t & 63;
    int mi = lane & 15, kq = lane >> 4;
    const float* src = A + (ct * 16 + mi) * DIN + step * 32 + kq * 8;
    *(uint4*)(Abp + ((size_t)(step * 4 + ct) * 64 + lane) * 8) = cvt8(src);
}

// ---- Kernel 4 (R9: SINGLE-PASS fused convert_x + lora_g):
// R8 read x TWICE (linear convert pass + fragment-order MFMA pass from L3).
// Now x is read ONCE per 320-col chunk: coalesced float4 loads -> cvt ->
// coalesced 8-B xb stores AND ds_write into a padded LDS tile; the MFMA path
// reads its fragments from LDS (on-chip, no second global read).
// LDS: xs[64][XS_STR=328] bf16 = 41 KB (stride 328: rows 16-B aligned; bank
// start 4*(mi+kq) mod 32 -> <=8-way on a rare op) UNIONED with hs[4][64][64]
// fp32 = 64 KB (hs only live after all chunks; __syncthreads separates).
// LDS 64 KB -> 2 blocks/CU (2048 thr, full occupancy). Traffic: 168 MB read
// + 84 MB xb + 4 MB g ~= 256 MB -> ~45-65 us.
// K-steps per chunk: 10; wave (kg,wv): wv = row-group, kg takes steps
// sl = kg+4j (j=0..; counts 3,3,2,2) -- partition of the 10 steps, acc sums
// across chunks, hs[kg] partials summed in the reduction as before.
__global__ __launch_bounds__(1024) void k_lora_g(const float* __restrict__ x,
                                                 const unsigned short* __restrict__ Abp,
                                                 const float* __restrict__ scalings,
                                                 const float* __restrict__ masks,
                                                 unsigned short* __restrict__ g,
                                                 unsigned short* __restrict__ xb) {
#define XS_STR 328
    __shared__ __align__(16) char sh[4 * 64 * 64 * 4];   // 64 KB union buffer
    unsigned short* xs = (unsigned short*)sh;            // [64][XS_STR] bf16
    float (*hs)[64][64] = (float (*)[64][64])sh;         // [4][64][64] fp32

    int tid = threadIdx.x;
    int wave = tid >> 6, lane = tid & 63;
    int kg = wave >> 2, wv = wave & 3;
    int mi = lane & 15, kq = lane >> 4;
    int m0 = blockIdx.x * 64;                 // 512 blocks

    floatx4 acc[4] = {};

    for (int c = 0; c < 4; ++c) {             // 4 chunks x 320 cols
        if (c) barx();                        // prev chunk's xs reads done
        // ---- stage: coalesced x load -> cvt -> xb store + ds_write
#pragma unroll
        for (int i = 0; i < 5; ++i) {
            int f = (i * 1024 + tid) * 4;     // flat float idx in 64x320 slab
            int row = f / 320;
            int col = f - row * 320;
            float4 v = *(const float4*)(x + (size_t)(m0 + row) * DIN + c * 320 + col);
            uint2 o = cvt4(v);
            *(uint2*)(xb + (size_t)(m0 + row) * DIN + c * 320 + col) = o;
            *(uint2*)(xs + row * XS_STR + col) = o;
        }
        barx();                               // xs visible to all waves
        // ---- MFMA: fragments from LDS, Abp from global (L2-hot)
        for (int j = 0; kg + 4 * j < 10; ++j) {
            int sl = kg + 4 * j;              // step-in-chunk
            int step = c * 10 + sl;           // global step 0..39
            shortx8 xf = *(const shortx8*)(xs + (wv * 16 + mi) * XS_STR + sl * 32 + kq * 8);
#pragma unroll
            for (int ct = 0; ct < 4; ++ct) {
                shortx8 bfr = *(const shortx8*)(Abp + ((size_t)(step * 4 + ct) * 64 + lane) * 8);
                acc[ct] = __builtin_amdgcn_mfma_f32_16x16x32_bf16(xf, bfr, acc[ct], 0, 0, 0);
            }
        }
    }
    __syncthreads();                          // xs dead; hs takes over the buffer

#pragma unroll
    for (int ct = 0; ct < 4; ++ct)
#pragma unroll
        for (int reg = 0; reg < 4; ++reg)
            hs[kg][wv * 16 + kq * 4 + reg][ct * 16 + mi] = acc[ct][reg];
    __syncthreads();

    int r = tid >> 4;                         // 0..63 local row
    int c0 = (tid & 15) * 4;                  // 0..60 rank col (4-aligned)
    float4 s0 = *(const float4*)&hs[0][r][c0];
    float4 s1 = *(const float4*)&hs[1][r][c0];
    float4 s2 = *(const float4*)&hs[2][r][c0];
    float4 s3 = *(const float4*)&hs[3][r][c0];
    int n = c0 >> 4;                          // adapter (c0..c0+3 share it)
    int m = m0 + r;
    float wgt = scalings[n] * masks[n * S_LEN + (m & (S_LEN - 1))];
    float v0 = (s0.x + s1.x + s2.x + s3.x) * wgt;
    float v1 = (s0.y + s1.y + s2.y + s3.y) * wgt;
    float v2 = (s0.z + s1.z + s2.z + s3.z) * wgt;
    float v3 = (s0.w + s1.w + s2.w + s3.w) * wgt;
    uint2 packed;
    packed.x = (unsigned)bf16_rne(v0) | ((unsigned)bf16_rne(v1) << 16);
    packed.y = (unsigned)bf16_rne(v2) | ((unsigned)bf16_rne(v3) << 16);
    *(uint2*)(g + (size_t)m * NR + c0) = packed;
#undef XS_STR
}

// ---- Kernel 5: out = [xb | g] @ Wcat^T + bias  (M=32768, N=1280, K=1344)
// R6 structure UNCHANGED — the measured plateau of this template family
// (143±5 us across R3/R4/R6/R8; coarser schedules R5/R7 and read-pipelining
// R4 all neutral-or-worse). Serves as the control channel this round.
// 8 waves (2M x 4N), BM=BN=256, BK=64, 2 K-tiles/iter, 8 phases/iter.
// Stage slots:  ph0: A(T1)h1   ph2: B(N0)h0   ph3: B(N0)h1+A(N0)h0 [VMCNT(6)]
//               ph4: A(N0)h1   ph6: B(N1)h0   ph7: B(N1)h1+A(N1)h0 [VMCNT(6)]
// VMCNT before bar2 (race-free). LDS swizzle: 16B-slot ^ (row&7), pre-swizzled
// global source; 0 conflicts measured.
__global__ __launch_bounds__(512, 2) void k_main_gemm(const unsigned short* __restrict__ xb,
                                                      const unsigned short* __restrict__ g,
                                                      const unsigned short* __restrict__ Wcat,
                                                      const float* __restrict__ bias,
                                                      float* __restrict__ out) {
    __shared__ alignas(16) unsigned short As[2][256 * 64];
    __shared__ alignas(16) unsigned short Bs[2][256 * 64];

    const int tid = threadIdx.x;
    const int wave = tid >> 6, lane = tid & 63;
    const int wm = wave >> 2, wn = wave & 3;        // 2M x 4N wave grid
    const int mi = lane & 15, kq = lane >> 4;

    int bx = blockIdx.x;
    int xcd = bx & 7, slot = bx >> 3;               // slot 0..79
    int srb = slot / 5;
    const int m0 = (xcd * 16 + srb) * 256;
    const int n0 = (slot - srb * 5) * 256;

    const int tr = tid >> 3;                        // row within chunk
    const int ts = (tid & 7) ^ (tr & 7);            // pre-swizzled 16B column slot

    const unsigned short* pA = xb   + (size_t)(m0 + tr) * DIN + ts * 8;
    const unsigned short* pG = g    + (size_t)(m0 + tr) * NR  + ts * 8;
    const unsigned short* pB = Wcat + (size_t)(n0 + tr) * KC  + ts * 8;

    const int swz  = mi & 7;
    const int loK0 = mi * 128 + (((0) + kq) ^ swz) * 16;   // k-sub 0
    const int loK1 = mi * 128 + (((4) + kq) ^ swz) * 16;   // k-sub 1
    const int rbA  = (wm * 128) * 128;              // wave A row-block byte offset
    const int rbB  = (wn * 64) * 128;               // wave B row-block byte offset

    floatx4 acc[8][4] = {};
    shortx8 a[8];                                   // current A-half: 4 m-frags x 2 ksubs
    shortx8 b[2][4];                                // B frags, ping-pong by nh

    auto stA = [&](int t, int h) {                  // stage A half h of tile t -> buf t&1
        unsigned short* d = &As[t & 1][(h * 128) * 64 + tid * 8];
        if (t < 20) {
            const unsigned short* s = pA + (size_t)(h * 128) * DIN + t * 64;
            async16(s, d);
            async16(s + (size_t)64 * DIN, d + 64 * 64);
        } else {                                    // tile 20 = LoRA columns from g
            const unsigned short* s = pG + (size_t)(h * 128) * NR;
            async16(s, d);
            async16(s + (size_t)64 * NR, d + 64 * 64);
        }
    };
    auto stB = [&](int t, int h) {
        const unsigned short* s = pB + (size_t)(h * 128) * KC + t * 64;
        unsigned short* d = &Bs[t & 1][(h * 128) * 64 + tid * 8];
        async16(s, d);
        async16(s + (size_t)64 * KC, d + 64 * 64);
    };

#define READ_A(bufb, mh)  _Pragma("unroll") \
    for (int fm = 0; fm < 4; ++fm) { \
        const char* p = (const char*)As[bufb] + rbA + ((mh) * 64 + fm * 16) * 128; \
        a[fm * 2 + 0] = *(const shortx8*)(p + loK0); \
        a[fm * 2 + 1] = *(const shortx8*)(p + loK1); \
    }
#define READ_B(bufb, nh)  _Pragma("unroll") \
    for (int fn = 0; fn < 2; ++fn) { \
        const char* p = (const char*)Bs[bufb] + rbB + ((nh) * 32 + fn * 16) * 128; \
        b[nh][fn * 2 + 0] = *(const shortx8*)(p + loK0); \
        b[nh][fn * 2 + 1] = *(const shortx8*)(p + loK1); \
    }
#define MFMA16(mh, nh)  do { __builtin_amdgcn_s_setprio(1); \
    _Pragma("unroll") \
    for (int fm = 0; fm < 4; ++fm) \
        _Pragma("unroll") \
        for (int fn = 0; fn < 2; ++fn) { \
            acc[(mh)*4+fm][(nh)*2+fn] = __builtin_amdgcn_mfma_f32_16x16x32_bf16( \
                a[fm*2+0], b[nh][fn*2+0], acc[(mh)*4+fm][(nh)*2+fn], 0, 0, 0); \
            acc[(mh)*4+fm][(nh)*2+fn] = __builtin_amdgcn_mfma_f32_16x16x32_bf16( \
                a[fm*2+1], b[nh][fn*2+1], acc[(mh)*4+fm][(nh)*2+fn], 0, 0, 0); \
        } \
    __builtin_amdgcn_s_setprio(0); } while (0)

    // prologue: tile0 (8 loads) then tile1's {Bh0, Bh1, Ah0} (6 loads).
    stA(0, 0); stA(0, 1); stB(0, 0); stB(0, 1);
    stB(1, 0); stB(1, 1); stA(1, 0);
    VMCNT(6);
    barx();

    for (int it = 0; it < 10; ++it) {
        const int T1 = 2 * it + 1, N0 = 2 * it + 2, N1 = 2 * it + 3;
        const bool lastI = (it == 9);

        // ---- phase 0: tile T0 (buf0) quad(0,0); stage A(T1)h1
        READ_A(0, 0); READ_B(0, 0);
        stA(T1, 1);
        barx();
        MFMA16(0, 0);
        barx();
        // ---- phase 1: quad(0,1)
        READ_B(0, 1);
        barx();
        MFMA16(0, 1);
        barx();
        // ---- phase 2: quad(1,0); stage B(N0)h0
        READ_A(0, 1);
        stB(N0, 0);
        barx();
        MFMA16(1, 0);
        barx();
        // ---- phase 3: quad(1,1); stage B(N0)h1 + A(N0)h0; VMCNT(6): T1 landed
        stB(N0, 1); stA(N0, 0);
        barx();
        MFMA16(1, 1);
        VMCNT(6);
        barx();
        // ---- phase 4: tile T1 (buf1) quad(0,0); stage A(N0)h1
        READ_A(1, 0); READ_B(1, 0);
        stA(N0, 1);
        barx();
        MFMA16(0, 0);
        barx();
        // ---- phase 5: quad(0,1)
        READ_B(1, 1);
        barx();
        MFMA16(0, 1);
        barx();
        // ---- phase 6: quad(1,0); stage B(N1)h0
        READ_A(1, 1);
        if (!lastI) stB(N1, 0);
        barx();
        MFMA16(1, 0);
        barx();
        // ---- phase 7: quad(1,1); stage B(N1)h1 + A(N1)h0; VMCNT(6): N0 landed
        if (!lastI) { stB(N1, 1); stA(N1, 0); }
        barx();
        MFMA16(1, 1);
        if (lastI) { VMCNT(0); } else { VMCNT(6); }
        barx();
    }

    // ---- tail: tile 20 (buf0), stage-free
    READ_A(0, 0); READ_B(0, 0);
    MFMA16(0, 0);
    READ_B(0, 1);
    MFMA16(0, 1);
    READ_A(0, 1);
    MFMA16(1, 0);
    MFMA16(1, 1);

    // ---- epilogue: C/D layout col = lane&15, row = (lane>>4)*4 + reg
    float bv[4];
#pragma unroll
    for (int nf = 0; nf < 4; ++nf)
        bv[nf] = bias[n0 + wn * 64 + (nf >> 1) * 32 + (nf & 1) * 16 + mi];
#pragma unroll
    for (int mf = 0; mf < 8; ++mf) {
        const int row = m0 + wm * 128 + (mf >> 2) * 64 + (mf & 3) * 16 + kq * 4;
#pragma unroll
        for (int nf = 0; nf < 4; ++nf) {
            const int col = n0 + wn * 64 + (nf >> 1) * 32 + (nf & 1) * 16 + mi;
            float* op = out + (size_t)row * DOUT + col;
#pragma unroll
            for (int reg = 0; reg < 4; ++reg)
                op[(size_t)reg * DOUT] = acc[mf][nf][reg] + bv[nf];
        }
    }
#undef READ_A
#undef READ_B
#undef MFMA16
}

extern "C" void kernel_launch(void* const* d_in, const int* in_sizes, int n_in,
                              void* d_out, int out_size, void* d_ws, size_t ws_size,
                              hipStream_t stream) {
    const float* x     = (const float*)d_in[0];  // (8,4096,1280)
    const float* W     = (const float*)d_in[1];  // (1280,1280)
    const float* bias  = (const float*)d_in[2];  // (1280,)
    const float* A     = (const float*)d_in[3];  // (4,16,1280)
    const float* Bw    = (const float*)d_in[4];  // (4,1280,16)
    const float* scal  = (const float*)d_in[5];  // (4,)
    const float* masks = (const float*)d_in[6];  // (4,4096)
    float* out = (float*)d_out;

    unsigned short* xb   = (unsigned short*)d_ws;            // 32768 x 1280 bf16
    unsigned short* g    = xb + (size_t)M_TOT * DIN;         // 32768 x 64 bf16
    unsigned short* Wcat = g + (size_t)M_TOT * NR;           // 1280 x 1344 bf16
    unsigned short* Abp  = Wcat + (size_t)DOUT * KC;         // 40*4*64*8 bf16

    k_build_wcat<<<(DOUT * KC) / (8 * 256), 256, 0, stream>>>(W, Bw, Wcat);
    k_convert_abp<<<DIN / 32, 256, 0, stream>>>(A, Abp);
    k_lora_g<<<M_TOT / 64, 1024, 0, stream>>>(x, Abp, scal, masks, g, xb);
    k_main_gemm<<<(M_TOT / 256) * (DOUT / 256), 512, 0, stream>>>(xb, g, Wcat, bias, out);
}